// Round 6
// baseline (820.299 us; speedup 1.0000x reference)
//
#include <hip/hip_runtime.h>

#define NEGV -1e9f

// workspace layout (float offsets)
#define OFF_X1   0u               // 1048576  emb@W_ih^T + b  (k2-only; k3 reuses as A_T)
#define OFF_XX   1048576u         // 1048576  emb@Wx^T + b_cell
#define OFF_A    2097152u         // 262144   Aemb = Ws_b + emb@Ws3^T (row-major)
#define OFF_SH   2359296u         // 262144   shared LSTM outputs
#define OFF_SWM  2621440u         // 1048576  shared@Wm^T
#define OFF_HX2  3670016u         // 16384 floats = 2 slots x 16 x 256 u64 (k2 h exchange)
#define OFF_HX4  3686400u         // 16384 floats (k4 h exchange)
#define OFF_PSI  3702784u         // 32768 floats = 2 slots x 16 x 512 u64 (k4 psi exchange)
#define OFF_AT   OFF_X1           // 262144   A transposed [b][k=256][s=64] (written by k3)

__device__ __forceinline__ float sigf(float x) { return 1.f / (1.f + __expf(-x)); }
__device__ __forceinline__ float tanhfast(float x) {
  float e = __expf(2.f * x);
  return 1.f - __fdividef(2.f, e + 1.f);
}

__device__ __forceinline__ unsigned long long gloadU64(const unsigned long long* p) {
  return __hip_atomic_load(p, __ATOMIC_RELAXED, __HIP_MEMORY_SCOPE_AGENT);
}
__device__ __forceinline__ void gstoreU64(unsigned long long* p, unsigned long long v) {
  __hip_atomic_store(p, v, __ATOMIC_RELAXED, __HIP_MEMORY_SCOPE_AGENT);
}
__device__ __forceinline__ unsigned long long packTV(unsigned tag, float v) {
  return ((unsigned long long)tag << 32) | (unsigned long long)__float_as_uint(v);
}

// 16-row x 128-col output tile GEMM helper, K=256. eL: [16][260], wL: [128][68]
__device__ __forceinline__ void tile_mm(const float* __restrict__ W, int ldw, int wcol0,
                                        int j0, const float* eL, float* wL, float acc[8]) {
  const int i = threadIdx.x >> 4, jj = threadIdx.x & 15;
  for (int kc = 0; kc < 4; ++kc) {
    __syncthreads();
    const int k0 = kc * 64;
    #pragma unroll
    for (int m = 0; m < 32; ++m) {
      int v = threadIdx.x + (m << 8);
      int row = v >> 6, col = v & 63;
      wL[row * 68 + col] = W[(j0 + row) * ldw + wcol0 + k0 + col];
    }
    __syncthreads();
    const float* ebase = eL + i * 260 + k0;
    #pragma unroll 4
    for (int k4 = 0; k4 < 16; ++k4) {
      float4 e4 = *(const float4*)(ebase + k4 * 4);
      #pragma unroll
      for (int u = 0; u < 8; ++u) {
        float4 w4 = *(const float4*)(wL + (jj + (u << 4)) * 68 + k4 * 4);
        acc[u] += e4.x * w4.x + e4.y * w4.y + e4.z * w4.z + e4.w * w4.w;
      }
    }
  }
}

// K1: emb gather + X1 = emb@W_ih^T + (b_ih+b_hh); Xx = emb@Wx^T + b_cell;
//     Aemb = emb@Ws3^T + Ws_b (row-major). Zero-inits all exchange buffers.
__global__ __launch_bounds__(256) void k1_precompute(
    const int* __restrict__ x, const float* __restrict__ embed,
    const float* __restrict__ W_ih, const float* __restrict__ b_ih,
    const float* __restrict__ b_hh, const float* __restrict__ Ws_w,
    const float* __restrict__ Ws_b, const float* __restrict__ Wx,
    const float* __restrict__ b_cell, float* __restrict__ ws) {
  __shared__ float eL[16 * 260];
  __shared__ float wL[128 * 68];
  const int rt = blockIdx.x / 18, jb = blockIdx.x % 18;
  if (blockIdx.x == 0) {
    for (int i = threadIdx.x; i < 65536; i += 256) ws[OFF_HX2 + i] = 0.f;
  }
  for (int i = 0; i < 16; ++i) {
    int xi = x[rt * 16 + i];
    eL[i * 260 + threadIdx.x] = embed[xi * 256 + threadIdx.x];
  }
  const float* W; const float* bias1; const float* bias2 = nullptr;
  int ldw, wcol0, j0, ostride; float* out;
  if (jb < 8)       { W = W_ih; ldw = 256; wcol0 = 0;   j0 = jb * 128;        out = ws + OFF_X1; ostride = 1024; bias1 = b_ih; bias2 = b_hh; }
  else if (jb < 16) { W = Wx;   ldw = 256; wcol0 = 0;   j0 = (jb - 8) * 128;  out = ws + OFF_XX; ostride = 1024; bias1 = b_cell; }
  else              { W = Ws_w; ldw = 768; wcol0 = 512; j0 = (jb - 16) * 128; out = ws + OFF_A;  ostride = 256;  bias1 = Ws_b; }
  float acc[8];
  #pragma unroll
  for (int u = 0; u < 8; ++u) acc[u] = 0.f;
  tile_mm(W, ldw, wcol0, j0, eL, wL, acc);
  const int i = threadIdx.x >> 4, jj = threadIdx.x & 15;
  const int r = rt * 16 + i;
  #pragma unroll
  for (int u = 0; u < 8; ++u) {
    int j = j0 + jj + (u << 4);
    float bv = bias1[j] + (bias2 ? bias2[j] : 0.f);
    out[r * ostride + j] = acc[u] + bv;
  }
}

// K2: shared LSTM, batch-paired. grid 64 = 8 pairs x 8 slices, 512 threads.
// Wave-local gates (4 gates of a hidden unit in one wave, shfl extraction).
// 2 syncs/step; combined A/B h-poll (one remote latency for both).
__global__ __launch_bounds__(512) void k2_shared_lstm(
    const float* __restrict__ W_hh, float* __restrict__ ws) {
  const int g = blockIdx.x & 7, j = blockIdx.x >> 3;
  const int bA = g << 1, bB = bA + 1;
  const int t = threadIdx.x;
  const int w = t >> 6, l = t & 63;
  const int gate = l >> 4, nnl = (w << 2) + ((l >> 2) & 3), q = l & 3;
  const int r = (gate << 5) + nnl;                  // local row 0..127
  const int grow = (gate << 8) + (j << 5) + nnl;    // global g row
  __shared__ float x1LA[8192], x1LB[8192];
  __shared__ __align__(16) float hLA[256], hLB[256];
  unsigned long long* hx = (unsigned long long*)(ws + OFF_HX2);
  float* sh = ws + OFF_SH;
  const float* X1 = ws + OFF_X1;

  float4 wv[16];
  {
    const float* wp = W_hh + grow * 256 + (q << 6);
    #pragma unroll
    for (int m = 0; m < 16; ++m) wv[m] = *(const float4*)(wp + 4 * m);
  }
  for (int v = t; v < 8192; v += 512) {
    int st = v >> 7, rr = v & 127;
    int col = ((rr >> 5) << 8) + (j << 5) + (rr & 31);
    x1LA[v] = X1[(bA * 64 + st) * 1024 + col];
    x1LB[v] = X1[(bB * 64 + st) * 1024 + col];
  }
  float cA = 0.f, cB = 0.f;
  const bool owner = (gate == 0) && (q == 0);
  __syncthreads();

  for (int st = 0; st < 64; ++st) {
    // combined h poll: threads 0-255 -> batch A, 256-511 -> batch B
    {
      int pb = t >> 8, e = t & 255, bb = bA + pb;
      const unsigned long long* p = hx + (unsigned)(st & 1) * 4096u + bb * 256 + e;
      unsigned long long v = gloadU64(p);
      while ((unsigned)(v >> 32) < (unsigned)st) v = gloadU64(p);
      (pb ? hLB : hLA)[e] = __uint_as_float((unsigned)v);
    }
    __syncthreads();
    // ---- batch A: gemm + wave-local gates + publish ----
    {
      const float* hp = hLA + (q << 6);
      float p = 0.f;
      #pragma unroll
      for (int m = 0; m < 16; ++m) {
        float4 h4 = *(const float4*)(hp + 4 * m);
        p += wv[m].x * h4.x + wv[m].y * h4.y + wv[m].z * h4.z + wv[m].w * h4.w;
      }
      if (q == 0) p += x1LA[(st << 7) + r];
      p += __shfl_xor(p, 1); p += __shfl_xor(p, 2);
      float gfv = __shfl(p, l + 16);
      float ggv = __shfl(p, l + 32);
      float gov = __shfl(p, l + 48);
      if (owner) {
        cA = sigf(gfv) * cA + sigf(p) * tanhfast(ggv);
        float hn = sigf(gov) * tanhfast(cA);
        sh[(bA * 64 + st) * 256 + (j << 5) + nnl] = hn;
        gstoreU64(hx + (unsigned)((st + 1) & 1) * 4096u + bA * 256 + (j << 5) + nnl,
                  packTV(st + 1, hn));
      }
    }
    // ---- batch B ----
    {
      const float* hp = hLB + (q << 6);
      float p = 0.f;
      #pragma unroll
      for (int m = 0; m < 16; ++m) {
        float4 h4 = *(const float4*)(hp + 4 * m);
        p += wv[m].x * h4.x + wv[m].y * h4.y + wv[m].z * h4.z + wv[m].w * h4.w;
      }
      if (q == 0) p += x1LB[(st << 7) + r];
      p += __shfl_xor(p, 1); p += __shfl_xor(p, 2);
      float gfv = __shfl(p, l + 16);
      float ggv = __shfl(p, l + 32);
      float gov = __shfl(p, l + 48);
      if (owner) {
        cB = sigf(gfv) * cB + sigf(p) * tanhfast(ggv);
        float hn = sigf(gov) * tanhfast(cB);
        sh[(bB * 64 + st) * 256 + (j << 5) + nnl] = hn;
        gstoreU64(hx + (unsigned)((st + 1) & 1) * 4096u + bB * 256 + (j << 5) + nnl,
                  packTV(st + 1, hn));
      }
    }
    __syncthreads();  // protect hLA/hLB against next step's poll overwrite
  }
}

// K3: A_T[b][k][s] = Aemb + shared@Ws1^T (transposed write into dead X1 buf);
//     SWM = shared@Wm^T (row-major as before).
__global__ __launch_bounds__(256) void k3_precompute2(
    const float* __restrict__ Ws_w, const float* __restrict__ Wm,
    float* __restrict__ ws) {
  __shared__ float eL[16 * 260];
  __shared__ float wL[128 * 68];
  const int rt = blockIdx.x / 10, jb = blockIdx.x % 10;
  const float* sh = ws + OFF_SH;
  for (int i = 0; i < 16; ++i)
    eL[i * 260 + threadIdx.x] = sh[(rt * 16 + i) * 256 + threadIdx.x];
  const float* W; int ldw, wcol0, j0; bool addmode;
  if (jb < 8) { W = Wm;   ldw = 256; wcol0 = 0; j0 = jb * 128;       addmode = false; }
  else        { W = Ws_w; ldw = 768; wcol0 = 0; j0 = (jb - 8) * 128; addmode = true; }
  float acc[8];
  #pragma unroll
  for (int u = 0; u < 8; ++u) acc[u] = 0.f;
  tile_mm(W, ldw, wcol0, j0, eL, wL, acc);
  const int i = threadIdx.x >> 4, jj = threadIdx.x & 15;
  const int r = rt * 16 + i;
  if (addmode) {
    const float* Aemb = ws + OFF_A;
    float* AT = ws + OFF_AT;
    const int bb = r >> 6, s = r & 63;
    #pragma unroll
    for (int u = 0; u < 8; ++u) {
      int j = j0 + jj + (u << 4);
      AT[bb * 16384 + j * 64 + s] = Aemb[r * 256 + j] + acc[u];
    }
  } else {
    float* out = ws + OFF_SWM;
    #pragma unroll
    for (int u = 0; u < 8; ++u) {
      int j = j0 + jj + (u << 4);
      out[r * 1024 + j] = acc[u];
    }
  }
}

// K4: task LSTM + attention, batch-paired. grid 64 = 8 pairs x 8 slices, 512 thr.
// 3 syncs/step; combined A/B polls; wave-local hw->psi and softmax->g->gates.
__global__ __launch_bounds__(512) void k4_task_lstm(
    const int* __restrict__ mask, const float* __restrict__ Ws_w,
    const float* __restrict__ Us_w, const float* __restrict__ Wh,
    const float* __restrict__ fc_w, const float* __restrict__ fc_b,
    float* __restrict__ ws, float* __restrict__ out) {
  const int g = blockIdx.x & 7, j = blockIdx.x >> 3;
  const int bA = g << 1, bB = bA + 1;
  const int t = threadIdx.x;
  const int w = t >> 6, l = t & 63;
  // g-phase mapping (all 4 gates of a hidden unit inside one wave)
  const int gate = l >> 4, nnl = (w << 2) + ((l >> 2) & 3), q = l & 3;
  const int r = (gate << 5) + nnl;
  const int grow = (gate << 8) + (j << 5) + nnl;
  // hw mapping: wave w owns hw rows [4w,4w+4), 16 lanes each
  const int hwrow = t >> 4, hwc = t & 15;

  __shared__ __align__(16) float swmBA[10240], swmBB[10240]; // 80 KiB
  __shared__ __align__(16) float aToA[2080], aToB[2080];     // 16.6 KiB
  __shared__ __align__(16) float hLA[256], hLB[256];
  __shared__ float usOwn[32];
  __shared__ float partA[512], partB[512];
  __shared__ float psiAA[512], psiAB[512];
  __shared__ float attWA[512], attWB[512];   // per-wave softmax copies
  __shared__ float redL[8];
  __shared__ int   mLA[64], mLB[64];

  unsigned long long* hx   = (unsigned long long*)(ws + OFF_HX4);
  unsigned long long* psiX = (unsigned long long*)(ws + OFF_PSI);
  const float* AT  = ws + OFF_AT;
  const float* SWM = ws + OFF_SWM;
  const float* Xx  = ws + OFF_XX;

  // ---- weights into registers (80 VGPR persistent) ----
  float4 w2v[4];    // Ws2 row (32j+hwrow), cols hwc*16..+16
  {
    const float* p2 = Ws_w + (j * 32 + hwrow) * 768 + 256 + (hwc << 4);
    #pragma unroll
    for (int m = 0; m < 4; ++m) w2v[m] = *(const float4*)(p2 + 4 * m);
  }
  float4 whv[16];   // Wh quarter-row (grow, cols q*64..+64)
  {
    const float* pw = Wh + grow * 256 + (q << 6);
    #pragma unroll
    for (int m = 0; m < 16; ++m) whv[m] = *(const float4*)(pw + 4 * m);
  }
  // ---- LDS staging (both batches) ----
  for (int v = t; v < 2048; v += 512) {
    aToA[(v >> 6) * 65 + (v & 63)] = AT[bA * 16384 + j * 2048 + v];
    aToB[(v >> 6) * 65 + (v & 63)] = AT[bB * 16384 + j * 2048 + v];
  }
  for (int v = t; v < 8192; v += 512) {
    int s = v >> 7, rr = v & 127;
    int col = ((rr >> 5) << 8) + (j << 5) + (rr & 31);
    int li = (s >> 4) * 2560 + rr * 20 + (s & 15);
    swmBA[li] = SWM[(bA * 64 + s) * 1024 + col];
    swmBB[li] = SWM[(bB * 64 + s) * 1024 + col];
  }
  if (t < 32) usOwn[t] = Us_w[j * 32 + t];
  if (t < 64) { mLA[t] = mask[bA * 64 + t]; mLB[t] = mask[bB * 64 + t]; }
  float cA = 0.f, cB = 0.f;
  __syncthreads();

  for (int st = 0; st < 64; ++st) {
    // early Xx prefetch (one per g-row, q==0 lanes)
    float xxA = 0.f, xxB = 0.f;
    if (q == 0) {
      xxA = Xx[(bA * 64 + st) * 1024 + grow];
      xxB = Xx[(bB * 64 + st) * 1024 + grow];
    }
    // ---- combined h poll ----
    {
      int pb = t >> 8, e = t & 255, bb = bA + pb;
      const unsigned long long* p = hx + (unsigned)(st & 1) * 4096u + bb * 256 + e;
      unsigned long long v = gloadU64(p);
      while ((unsigned)(v >> 32) < (unsigned)st) v = gloadU64(p);
      (pb ? hLB : hLA)[e] = __uint_as_float((unsigned)v);
    }
    __syncthreads();                                     // sync 1
    // ---- hw + psi partials, batch A (wave-local) ----
    {
      const float* hp = hLA + (hwc << 4);
      float ph = 0.f;
      #pragma unroll
      for (int m = 0; m < 4; ++m) {
        float4 h4 = *(const float4*)(hp + 4 * m);
        ph += w2v[m].x * h4.x + w2v[m].y * h4.y + w2v[m].z * h4.z + w2v[m].w * h4.w;
      }
      ph += __shfl_xor(ph, 1); ph += __shfl_xor(ph, 2);
      ph += __shfl_xor(ph, 4); ph += __shfl_xor(ph, 8);
      float ps = 0.f;
      #pragma unroll
      for (int i2 = 0; i2 < 4; ++i2) {
        float hwv = __shfl(ph, i2 << 4);                 // hw row 4w+i2
        int kk = (w << 2) + i2;
        ps += usOwn[kk] * tanhfast(aToA[kk * 65 + l] + hwv);
      }
      partA[(w << 6) + l] = ps;
    }
    // ---- hw + psi partials, batch B ----
    {
      const float* hp = hLB + (hwc << 4);
      float ph = 0.f;
      #pragma unroll
      for (int m = 0; m < 4; ++m) {
        float4 h4 = *(const float4*)(hp + 4 * m);
        ph += w2v[m].x * h4.x + w2v[m].y * h4.y + w2v[m].z * h4.z + w2v[m].w * h4.w;
      }
      ph += __shfl_xor(ph, 1); ph += __shfl_xor(ph, 2);
      ph += __shfl_xor(ph, 4); ph += __shfl_xor(ph, 8);
      float ps = 0.f;
      #pragma unroll
      for (int i2 = 0; i2 < 4; ++i2) {
        float hwv = __shfl(ph, i2 << 4);
        int kk = (w << 2) + i2;
        ps += usOwn[kk] * tanhfast(aToB[kk * 65 + l] + hwv);
      }
      partB[(w << 6) + l] = ps;
    }
    __syncthreads();                                     // sync 2
    // ---- reduce + publish psi (wave 0) ----
    if (t < 64) {
      float psa = 0.f, psb = 0.f;
      #pragma unroll
      for (int w2 = 0; w2 < 8; ++w2) { psa += partA[(w2 << 6) + t]; psb += partB[(w2 << 6) + t]; }
      gstoreU64(psiX + ((unsigned)(st & 1) * 16u + bA) * 512u + (j << 6) + t, packTV(st + 1, psa));
      gstoreU64(psiX + ((unsigned)(st & 1) * 16u + bB) * 512u + (j << 6) + t, packTV(st + 1, psb));
    }
    // ---- h@Wh^T quarter-partials (fills psi-pub -> psi-poll gap) ----
    float pwhA = 0.f, pwhB = 0.f;
    {
      const float* ha = hLA + (q << 6);
      const float* hb = hLB + (q << 6);
      #pragma unroll
      for (int m = 0; m < 16; ++m) {
        float4 h4 = *(const float4*)(ha + 4 * m);
        float4 g4 = *(const float4*)(hb + 4 * m);
        pwhA += whv[m].x * h4.x + whv[m].y * h4.y + whv[m].z * h4.z + whv[m].w * h4.w;
        pwhB += whv[m].x * g4.x + whv[m].y * g4.y + whv[m].z * g4.z + whv[m].w * g4.w;
      }
    }
    // ---- combined psi poll (both loads in flight) ----
    {
      const unsigned long long* pa = psiX + ((unsigned)(st & 1) * 16u + bA) * 512u + t;
      const unsigned long long* pb = psiX + ((unsigned)(st & 1) * 16u + bB) * 512u + t;
      unsigned long long va = gloadU64(pa);
      unsigned long long vb = gloadU64(pb);
      while ((unsigned)(va >> 32) < (unsigned)(st + 1)) va = gloadU64(pa);
      while ((unsigned)(vb >> 32) < (unsigned)(st + 1)) vb = gloadU64(pb);
      psiAA[t] = __uint_as_float((unsigned)va);
      psiAB[t] = __uint_as_float((unsigned)vb);
    }
    __syncthreads();                                     // sync 3
    // ---- batch A: per-wave softmax -> g -> gates -> publish h ----
    {
      float vr = 0.f;
      #pragma unroll
      for (int w2 = 0; w2 < 8; ++w2) vr += psiAA[(w2 << 6) + l];
      vr = mLA[l] ? vr : NEGV;
      float mx = vr;
      #pragma unroll
      for (int d = 1; d < 64; d <<= 1) mx = fmaxf(mx, __shfl_xor(mx, d));
      float e2 = __expf(vr - mx);
      float ssum = e2;
      #pragma unroll
      for (int d = 1; d < 64; d <<= 1) ssum += __shfl_xor(ssum, d);
      attWA[(w << 6) + l] = e2 / ssum;
      float p = pwhA;
      const float* sb = swmBA + q * 2560 + r * 20;
      const float* ab = attWA + (w << 6) + (q << 4);
      #pragma unroll
      for (int i2 = 0; i2 < 4; ++i2) {
        float4 s4 = *(const float4*)(sb + 4 * i2);
        float4 a4 = *(const float4*)(ab + 4 * i2);
        p += s4.x * a4.x + s4.y * a4.y + s4.z * a4.z + s4.w * a4.w;
      }
      if (q == 0) p += xxA;
      p += __shfl_xor(p, 1); p += __shfl_xor(p, 2);
      float gfv = __shfl(p, l + 16);
      float ggv = __shfl(p, l + 32);
      float gov = __shfl(p, l + 48);
      if (gate == 0 && q == 0) {
        cA = sigf(gfv) * cA + sigf(p) * tanhfast(ggv);
        float hn = sigf(gov) * tanhfast(cA);
        gstoreU64(hx + (unsigned)((st + 1) & 1) * 4096u + bA * 256 + (j << 5) + nnl,
                  packTV(st + 1, hn));
      }
    }
    // ---- batch B ----
    {
      float vr = 0.f;
      #pragma unroll
      for (int w2 = 0; w2 < 8; ++w2) vr += psiAB[(w2 << 6) + l];
      vr = mLB[l] ? vr : NEGV;
      float mx = vr;
      #pragma unroll
      for (int d = 1; d < 64; d <<= 1) mx = fmaxf(mx, __shfl_xor(mx, d));
      float e2 = __expf(vr - mx);
      float ssum = e2;
      #pragma unroll
      for (int d = 1; d < 64; d <<= 1) ssum += __shfl_xor(ssum, d);
      attWB[(w << 6) + l] = e2 / ssum;
      float p = pwhB;
      const float* sb = swmBB + q * 2560 + r * 20;
      const float* ab = attWB + (w << 6) + (q << 4);
      #pragma unroll
      for (int i2 = 0; i2 < 4; ++i2) {
        float4 s4 = *(const float4*)(sb + 4 * i2);
        float4 a4 = *(const float4*)(ab + 4 * i2);
        p += s4.x * a4.x + s4.y * a4.y + s4.z * a4.z + s4.w * a4.w;
      }
      if (q == 0) p += xxB;
      p += __shfl_xor(p, 1); p += __shfl_xor(p, 2);
      float gfv = __shfl(p, l + 16);
      float ggv = __shfl(p, l + 32);
      float gov = __shfl(p, l + 48);
      if (gate == 0 && q == 0) {
        cB = sigf(gfv) * cB + sigf(p) * tanhfast(ggv);
        float hn = sigf(gov) * tanhfast(cB);
        gstoreU64(hx + (unsigned)((st + 1) & 1) * 4096u + bB * 256 + (j << 5) + nnl,
                  packTV(st + 1, hn));
      }
    }
  }

  // ---- final classifier (WG j==0 per pair, both batches) ----
  if (j == 0) {
    float vA = 0.f, vB = 0.f;
    if (t < 256) {
      const unsigned long long* p0 = hx + bA * 256 + t;   // slot 0 (tag 64)
      unsigned long long v0 = gloadU64(p0);
      while ((unsigned)(v0 >> 32) < 64u) v0 = gloadU64(p0);
      vA = __uint_as_float((unsigned)v0) * fc_w[t];
      const unsigned long long* p1 = hx + bB * 256 + t;
      unsigned long long v1 = gloadU64(p1);
      while ((unsigned)(v1 >> 32) < 64u) v1 = gloadU64(p1);
      vB = __uint_as_float((unsigned)v1) * fc_w[t];
    }
    #pragma unroll
    for (int d = 1; d < 64; d <<= 1) { vA += __shfl_xor(vA, d); vB += __shfl_xor(vB, d); }
    if (t < 256 && (t & 63) == 0) { redL[t >> 6] = vA; redL[4 + (t >> 6)] = vB; }
    __syncthreads();
    if (t == 0) {
      out[bA] = sigf(redL[0] + redL[1] + redL[2] + redL[3] + fc_b[0]);
      out[bB] = sigf(redL[4] + redL[5] + redL[6] + redL[7] + fc_b[0]);
    }
  }
}

extern "C" void kernel_launch(void* const* d_in, const int* in_sizes, int n_in,
                              void* d_out, int out_size, void* d_ws, size_t ws_size,
                              hipStream_t stream) {
  const int*   x      = (const int*)d_in[0];
  const int*   mask   = (const int*)d_in[1];
  const float* embed  = (const float*)d_in[3];
  const float* W_ih   = (const float*)d_in[4];
  const float* W_hh   = (const float*)d_in[5];
  const float* b_ih   = (const float*)d_in[6];
  const float* b_hh   = (const float*)d_in[7];
  const float* Ws_w   = (const float*)d_in[8];
  const float* Ws_b   = (const float*)d_in[9];
  const float* Us_w   = (const float*)d_in[10];
  const float* Wx     = (const float*)d_in[12];
  const float* Wh     = (const float*)d_in[13];
  const float* Wm     = (const float*)d_in[14];
  const float* b_cell = (const float*)d_in[15];
  const float* fc_w   = (const float*)d_in[16];
  const float* fc_b   = (const float*)d_in[17];
  float* ws  = (float*)d_ws;
  float* out = (float*)d_out;

  k1_precompute<<<dim3(1152), dim3(256), 0, stream>>>(
      x, embed, W_ih, b_ih, b_hh, Ws_w, Ws_b, Wx, b_cell, ws);
  k2_shared_lstm<<<dim3(64), dim3(512), 0, stream>>>(W_hh, ws);
  k3_precompute2<<<dim3(640), dim3(256), 0, stream>>>(Ws_w, Wm, ws);
  k4_task_lstm<<<dim3(64), dim3(512), 0, stream>>>(
      mask, Ws_w, Us_w, Wh, fc_w, fc_b, ws, out);
}

// Round 7
// 806.717 us; speedup vs baseline: 1.0168x; 1.0168x over previous
//
#include <hip/hip_runtime.h>

#define NEGV -1e9f

// workspace layout (float offsets)
#define OFF_X1   0u               // 1048576  emb@W_ih^T + b (k2-only; k3 reuses head as A_T)
#define OFF_HWX  262144u          // 131072 floats = 65536 u64 hwpart exchange (dead X1 region, zeroed by k3)
#define OFF_XX   1048576u         // 1048576  emb@Wx^T + b_cell
#define OFF_A    2097152u         // 262144   Aemb = Ws_b + emb@Ws3^T (row-major)
#define OFF_SH   2359296u         // 262144   shared LSTM outputs
#define OFF_SWM  2621440u         // 1048576  shared@Wm^T
#define OFF_HX2  3670016u         // 16384 floats = 8192 u64 (k2 h exchange)
#define OFF_HX4  3686400u         // 16384 floats (k4 h exchange)
#define OFF_AT   OFF_X1           // 262144   A transposed [b][k=256][s=64] (written by k3)

__device__ __forceinline__ float sigf(float x) { return 1.f / (1.f + __expf(-x)); }
__device__ __forceinline__ float tanhfast(float x) {
  float e = __expf(2.f * x);
  return 1.f - __fdividef(2.f, e + 1.f);
}

__device__ __forceinline__ unsigned long long gloadU64(const unsigned long long* p) {
  return __hip_atomic_load(p, __ATOMIC_RELAXED, __HIP_MEMORY_SCOPE_AGENT);
}
__device__ __forceinline__ void gstoreU64(unsigned long long* p, unsigned long long v) {
  __hip_atomic_store(p, v, __ATOMIC_RELAXED, __HIP_MEMORY_SCOPE_AGENT);
}
__device__ __forceinline__ unsigned long long packTV(unsigned tag, float v) {
  return ((unsigned long long)tag << 32) | (unsigned long long)__float_as_uint(v);
}

// 16-row x 128-col output tile GEMM helper, K=256. eL: [16][260], wL: [128][68]
__device__ __forceinline__ void tile_mm(const float* __restrict__ W, int ldw, int wcol0,
                                        int j0, const float* eL, float* wL, float acc[8]) {
  const int i = threadIdx.x >> 4, jj = threadIdx.x & 15;
  for (int kc = 0; kc < 4; ++kc) {
    __syncthreads();
    const int k0 = kc * 64;
    #pragma unroll
    for (int m = 0; m < 32; ++m) {
      int v = threadIdx.x + (m << 8);
      int row = v >> 6, col = v & 63;
      wL[row * 68 + col] = W[(j0 + row) * ldw + wcol0 + k0 + col];
    }
    __syncthreads();
    const float* ebase = eL + i * 260 + k0;
    #pragma unroll 4
    for (int k4 = 0; k4 < 16; ++k4) {
      float4 e4 = *(const float4*)(ebase + k4 * 4);
      #pragma unroll
      for (int u = 0; u < 8; ++u) {
        float4 w4 = *(const float4*)(wL + (jj + (u << 4)) * 68 + k4 * 4);
        acc[u] += e4.x * w4.x + e4.y * w4.y + e4.z * w4.z + e4.w * w4.w;
      }
    }
  }
}

// K1: emb gather + X1 = emb@W_ih^T + (b_ih+b_hh); Xx = emb@Wx^T + b_cell;
//     Aemb = emb@Ws3^T + Ws_b. Zero-inits both h exchange buffers.
__global__ __launch_bounds__(256) void k1_precompute(
    const int* __restrict__ x, const float* __restrict__ embed,
    const float* __restrict__ W_ih, const float* __restrict__ b_ih,
    const float* __restrict__ b_hh, const float* __restrict__ Ws_w,
    const float* __restrict__ Ws_b, const float* __restrict__ Wx,
    const float* __restrict__ b_cell, float* __restrict__ ws) {
  __shared__ float eL[16 * 260];
  __shared__ float wL[128 * 68];
  const int rt = blockIdx.x / 18, jb = blockIdx.x % 18;
  if (blockIdx.x == 0) {
    for (int i = threadIdx.x; i < 32768; i += 256) ws[OFF_HX2 + i] = 0.f;
  }
  for (int i = 0; i < 16; ++i) {
    int xi = x[rt * 16 + i];
    eL[i * 260 + threadIdx.x] = embed[xi * 256 + threadIdx.x];
  }
  const float* W; const float* bias1; const float* bias2 = nullptr;
  int ldw, wcol0, j0, ostride; float* out;
  if (jb < 8)       { W = W_ih; ldw = 256; wcol0 = 0;   j0 = jb * 128;        out = ws + OFF_X1; ostride = 1024; bias1 = b_ih; bias2 = b_hh; }
  else if (jb < 16) { W = Wx;   ldw = 256; wcol0 = 0;   j0 = (jb - 8) * 128;  out = ws + OFF_XX; ostride = 1024; bias1 = b_cell; }
  else              { W = Ws_w; ldw = 768; wcol0 = 512; j0 = (jb - 16) * 128; out = ws + OFF_A;  ostride = 256;  bias1 = Ws_b; }
  float acc[8];
  #pragma unroll
  for (int u = 0; u < 8; ++u) acc[u] = 0.f;
  tile_mm(W, ldw, wcol0, j0, eL, wL, acc);
  const int i = threadIdx.x >> 4, jj = threadIdx.x & 15;
  const int r = rt * 16 + i;
  #pragma unroll
  for (int u = 0; u < 8; ++u) {
    int j = j0 + jj + (u << 4);
    float bv = bias1[j] + (bias2 ? bias2[j] : 0.f);
    out[r * ostride + j] = acc[u] + bv;
  }
}

// K2: shared LSTM. grid 128 = 16 batches x 8 WGs, 512 threads.
// Wave-autonomous: each lane polls h[4l..4l+4); h distributed by shfl; gates
// wave-local. ZERO barriers in the step loop, one LLC round-trip per step.
__global__ __launch_bounds__(512) void k2_shared_lstm(
    const float* __restrict__ W_hh, float* __restrict__ ws) {
  const int b = blockIdx.x & 15, j = blockIdx.x >> 4;
  const int t = threadIdx.x;
  const int w = t >> 6, l = t & 63;
  const int gate = l >> 4, u = (l >> 2) & 3, q = l & 3;
  const int nnl = (w << 2) + u;
  const int r = (gate << 5) + nnl;
  const int grow = (gate << 8) + (j << 5) + nnl;
  __shared__ float x1L[8192];
  unsigned long long* hx = (unsigned long long*)(ws + OFF_HX2);
  float* sh = ws + OFF_SH;
  const float* X1 = ws + OFF_X1;

  float4 wv[16];
  {
    const float* wp = W_hh + grow * 256 + (q << 6);
    #pragma unroll
    for (int m = 0; m < 16; ++m) wv[m] = *(const float4*)(wp + 4 * m);
  }
  for (int v = t; v < 8192; v += 512) {
    int st = v >> 7, rr = v & 127;
    int col = ((rr >> 5) << 8) + (j << 5) + (rr & 31);
    x1L[v] = X1[(b * 64 + st) * 1024 + col];
  }
  float c_reg = 0.f;
  const bool owner = (gate == 0) && (q == 0);
  __syncthreads();

  for (int st = 0; st < 64; ++st) {
    const unsigned long long* pp = hx + (unsigned)(st & 1) * 4096u + b * 256 + (l << 2);
    unsigned long long v0 = gloadU64(pp),     v1 = gloadU64(pp + 1),
                       v2 = gloadU64(pp + 2), v3 = gloadU64(pp + 3);
    while ((unsigned)(v0 >> 32) < (unsigned)st) v0 = gloadU64(pp);
    while ((unsigned)(v1 >> 32) < (unsigned)st) v1 = gloadU64(pp + 1);
    while ((unsigned)(v2 >> 32) < (unsigned)st) v2 = gloadU64(pp + 2);
    while ((unsigned)(v3 >> 32) < (unsigned)st) v3 = gloadU64(pp + 3);
    float h0 = __uint_as_float((unsigned)v0);
    float h1 = __uint_as_float((unsigned)v1);
    float h2 = __uint_as_float((unsigned)v2);
    float h3 = __uint_as_float((unsigned)v3);
    float p = 0.f;
    #pragma unroll
    for (int m = 0; m < 16; ++m) {
      int src = (q << 4) + m;
      p += wv[m].x * __shfl(h0, src) + wv[m].y * __shfl(h1, src)
         + wv[m].z * __shfl(h2, src) + wv[m].w * __shfl(h3, src);
    }
    if (q == 0) p += x1L[(st << 7) + r];
    p += __shfl_xor(p, 1); p += __shfl_xor(p, 2);
    float gf = __shfl(p, l + 16);
    float gg = __shfl(p, l + 32);
    float go = __shfl(p, l + 48);
    if (owner) {
      c_reg = sigf(gf) * c_reg + sigf(p) * tanhfast(gg);
      float hn = sigf(go) * tanhfast(c_reg);
      sh[(b * 64 + st) * 256 + (j << 5) + nnl] = hn;
      gstoreU64(hx + (unsigned)((st + 1) & 1) * 4096u + b * 256 + (j << 5) + nnl,
                packTV(st + 1, hn));
    }
  }
}

// K3: A_T[b][k][s] = Aemb + shared@Ws1^T (transposed into dead X1 head);
//     SWM = shared@Wm^T. jb==0 blocks also zero the hwpart exchange buffer.
__global__ __launch_bounds__(256) void k3_precompute2(
    const float* __restrict__ Ws_w, const float* __restrict__ Wm,
    float* __restrict__ ws) {
  __shared__ float eL[16 * 260];
  __shared__ float wL[128 * 68];
  const int rt = blockIdx.x / 10, jb = blockIdx.x % 10;
  if (jb == 0) {
    for (int i = threadIdx.x; i < 2048; i += 256) ws[OFF_HWX + rt * 2048 + i] = 0.f;
  }
  const float* sh = ws + OFF_SH;
  for (int i = 0; i < 16; ++i)
    eL[i * 260 + threadIdx.x] = sh[(rt * 16 + i) * 256 + threadIdx.x];
  const float* W; int ldw, wcol0, j0; bool addmode;
  if (jb < 8) { W = Wm;   ldw = 256; wcol0 = 0; j0 = jb * 128;       addmode = false; }
  else        { W = Ws_w; ldw = 768; wcol0 = 0; j0 = (jb - 8) * 128; addmode = true; }
  float acc[8];
  #pragma unroll
  for (int u = 0; u < 8; ++u) acc[u] = 0.f;
  tile_mm(W, ldw, wcol0, j0, eL, wL, acc);
  const int i = threadIdx.x >> 4, jj = threadIdx.x & 15;
  const int r = rt * 16 + i;
  if (addmode) {
    const float* Aemb = ws + OFF_A;
    float* AT = ws + OFF_AT;
    const int bb = r >> 6, s = r & 63;
    #pragma unroll
    for (int u = 0; u < 8; ++u) {
      int j = j0 + jj + (u << 4);
      AT[bb * 16384 + j * 64 + s] = Aemb[r * 256 + j] + acc[u];
    }
  } else {
    float* out = ws + OFF_SWM;
    #pragma unroll
    for (int u = 0; u < 8; ++u) {
      int j = j0 + jj + (u << 4);
      out[r * 1024 + j] = acc[u];
    }
  }
}

// K4: task LSTM + attention. grid 128 = 16 batches x 8 WGs, 512 threads.
// ONE LLC round-trip per step: {h, hwpart_j = Ws2[:,32j:32j+32]. h_slice}
// published together at step end, polled together at step start. Si/softmax
// computed locally (full A^T in LDS). 2 barriers/step.
__global__ __launch_bounds__(512) void k4_task_lstm(
    const int* __restrict__ mask, const float* __restrict__ Ws_w,
    const float* __restrict__ Us_w, const float* __restrict__ Wh,
    const float* __restrict__ fc_w, const float* __restrict__ fc_b,
    float* __restrict__ ws, float* __restrict__ out) {
  const int b = blockIdx.x & 15, j = blockIdx.x >> 4;
  const int t = threadIdx.x;
  const int w = t >> 6, l = t & 63;
  const int gate = l >> 4, u = (l >> 2) & 3, q = l & 3;
  const int nnl = (w << 2) + u;
  const int r = (gate << 5) + nnl;
  const int grow = (gate << 8) + (j << 5) + nnl;
  const int pr = t >> 1, kh = t & 1;     // hw row / k-half (wave-aligned: pr in [32w,32w+32))

  __shared__ __align__(16) float aT[256 * 65];     // 66560 B  A^T [k][s] pad65
  __shared__ __align__(16) float swmB[10240];      // 40960 B  [s/16][r][16]
  __shared__ __align__(16) float usL[256];
  __shared__ float hwL[256];                       // wave-private ranges
  __shared__ float part[512];
  __shared__ __align__(16) float attW[512];        // per-wave softmax copies
  __shared__ float hnewL[32];
  __shared__ float redL[4];
  __shared__ int   mL[64];

  unsigned long long* hx  = (unsigned long long*)(ws + OFF_HX4);
  unsigned long long* hwX = (unsigned long long*)(ws + OFF_HWX);
  const float* AT  = ws + OFF_AT;
  const float* SWM = ws + OFF_SWM;
  const float* Xx  = ws + OFF_XX;

  // ---- weights into registers (80 VGPR persistent) ----
  float4 whv[16];   // Wh quarter-row (grow, cols q*64..+64)
  {
    const float* pw = Wh + grow * 256 + (q << 6);
    #pragma unroll
    for (int m = 0; m < 16; ++m) whv[m] = *(const float4*)(pw + 4 * m);
  }
  float4 w2c[4];    // Ws2 row pr, cols (32j+16kh)..+16 (for next-step hwpart)
  {
    const float* p2 = Ws_w + pr * 768 + 256 + (j << 5) + (kh << 4);
    #pragma unroll
    for (int m = 0; m < 4; ++m) w2c[m] = *(const float4*)(p2 + 4 * m);
  }
  // ---- LDS staging ----
  for (int v = t; v < 16384; v += 512)
    aT[(v >> 6) * 65 + (v & 63)] = AT[b * 16384 + v];
  for (int v = t; v < 8192; v += 512) {
    int s = v >> 7, rr = v & 127;
    int col = ((rr >> 5) << 8) + (j << 5) + (rr & 31);
    swmB[(s >> 4) * 2560 + rr * 20 + (s & 15)] = SWM[(b * 64 + s) * 1024 + col];
  }
  if (t < 256) usL[t] = Us_w[t];
  if (t < 64) mL[t] = mask[b * 64 + t];
  float c_reg = 0.f;
  const bool owner = (gate == 0) && (q == 0);
  __syncthreads();

  for (int st = 0; st < 64; ++st) {
    float xx_r = (q == 0) ? Xx[(b * 64 + st) * 1024 + grow] : 0.f;
    // ---- combined poll: 4 h elements (lane quad) + 4 hwpart producers ----
    const unsigned long long* ph = hx + (unsigned)(st & 1) * 4096u + b * 256 + (l << 2);
    const unsigned long long* pw = hwX + b * 4096u + (unsigned)(st & 1) * 2048u
                                 + (kh << 10) + pr;
    unsigned long long a0 = gloadU64(pw),       a1 = gloadU64(pw + 256),
                       a2 = gloadU64(pw + 512), a3 = gloadU64(pw + 768);
    unsigned long long v0 = gloadU64(ph),     v1 = gloadU64(ph + 1),
                       v2 = gloadU64(ph + 2), v3 = gloadU64(ph + 3);
    while ((unsigned)(v0 >> 32) < (unsigned)st) v0 = gloadU64(ph);
    while ((unsigned)(v1 >> 32) < (unsigned)st) v1 = gloadU64(ph + 1);
    while ((unsigned)(v2 >> 32) < (unsigned)st) v2 = gloadU64(ph + 2);
    while ((unsigned)(v3 >> 32) < (unsigned)st) v3 = gloadU64(ph + 3);
    while ((unsigned)(a0 >> 32) < (unsigned)st) a0 = gloadU64(pw);
    while ((unsigned)(a1 >> 32) < (unsigned)st) a1 = gloadU64(pw + 256);
    while ((unsigned)(a2 >> 32) < (unsigned)st) a2 = gloadU64(pw + 512);
    while ((unsigned)(a3 >> 32) < (unsigned)st) a3 = gloadU64(pw + 768);
    float h0 = __uint_as_float((unsigned)v0);
    float h1 = __uint_as_float((unsigned)v1);
    float h2 = __uint_as_float((unsigned)v2);
    float h3 = __uint_as_float((unsigned)v3);
    {
      float s_hw = __uint_as_float((unsigned)a0) + __uint_as_float((unsigned)a1)
                 + __uint_as_float((unsigned)a2) + __uint_as_float((unsigned)a3);
      s_hw += __shfl_xor(s_hw, 1);
      if (kh == 0) hwL[pr] = s_hw;   // wave-private range [32w,32w+32)
    }
    // ---- psi partials over own k-chunk (wave-local; no barrier needed) ----
    float ps = 0.f;
    {
      const int k0 = w << 5;
      #pragma unroll
      for (int i = 0; i < 32; ++i) {
        int k = k0 + i;
        ps += usL[k] * tanhfast(aT[k * 65 + l] + hwL[k]);
      }
      part[t] = ps;
    }
    // ---- pwh = h@Wh^T quarter-dot via shfl-distributed h ----
    float pwh = 0.f;
    #pragma unroll
    for (int m = 0; m < 16; ++m) {
      int src = (q << 4) + m;
      pwh += whv[m].x * __shfl(h0, src) + whv[m].y * __shfl(h1, src)
           + whv[m].z * __shfl(h2, src) + whv[m].w * __shfl(h3, src);
    }
    __syncthreads();                                   // sync A: part[] complete
    // ---- Si assembly + mask + softmax (replicated per wave) ----
    {
      float vr = 0.f;
      #pragma unroll
      for (int w2 = 0; w2 < 8; ++w2) vr += part[(w2 << 6) + l];
      vr = mL[l] ? vr : NEGV;
      float mx = vr;
      #pragma unroll
      for (int d = 1; d < 64; d <<= 1) mx = fmaxf(mx, __shfl_xor(mx, d));
      float e2 = __expf(vr - mx);
      float ssum = e2;
      #pragma unroll
      for (int d = 1; d < 64; d <<= 1) ssum += __shfl_xor(ssum, d);
      attW[t] = e2 / ssum;       // wave-private copy, same-wave read below
    }
    // ---- g = xx + pwh + att@SWM; wave-local gates; publish h ----
    {
      float p = pwh;
      const float* sb = swmB + q * 2560 + r * 20;
      const float* ab = attW + (w << 6) + (q << 4);
      #pragma unroll
      for (int i2 = 0; i2 < 4; ++i2) {
        float4 s4 = *(const float4*)(sb + 4 * i2);
        float4 a4 = *(const float4*)(ab + 4 * i2);
        p += s4.x * a4.x + s4.y * a4.y + s4.z * a4.z + s4.w * a4.w;
      }
      if (q == 0) p += xx_r;
      p += __shfl_xor(p, 1); p += __shfl_xor(p, 2);
      float gf = __shfl(p, l + 16);
      float gg = __shfl(p, l + 32);
      float go = __shfl(p, l + 48);
      if (owner) {
        c_reg = sigf(gf) * c_reg + sigf(p) * tanhfast(gg);
        float hn = sigf(go) * tanhfast(c_reg);
        gstoreU64(hx + (unsigned)((st + 1) & 1) * 4096u + b * 256 + (j << 5) + nnl,
                  packTV(st + 1, hn));
        hnewL[nnl] = hn;
      }
    }
    // ---- next-step hwpart from own new h slice ----
    if (st < 63) {
      __syncthreads();                                 // sync B: hnewL complete
      const float* hb = hnewL + (kh << 4);
      float p2 = 0.f;
      #pragma unroll
      for (int m = 0; m < 4; ++m) {
        p2 += w2c[m].x * hb[4 * m]     + w2c[m].y * hb[4 * m + 1]
            + w2c[m].z * hb[4 * m + 2] + w2c[m].w * hb[4 * m + 3];
      }
      p2 += __shfl_xor(p2, 1);
      if (kh == 0)
        gstoreU64(hwX + b * 4096u + (unsigned)((st + 1) & 1) * 2048u + (j << 8) + pr,
                  packTV(st + 1, p2));
    }
  }

  // ---- final classifier (WG j==0 per batch) ----
  if (j == 0) {
    float v = 0.f;
    if (t < 256) {
      const unsigned long long* p = hx + 0 * 4096u + b * 256 + t;  // slot 64&1==0
      unsigned long long vv = gloadU64(p);
      while ((unsigned)(vv >> 32) < 64u) vv = gloadU64(p);
      v = __uint_as_float((unsigned)vv) * fc_w[t];
    }
    #pragma unroll
    for (int d = 1; d < 64; d <<= 1) v += __shfl_xor(v, d);
    if (t < 256 && (t & 63) == 0) redL[t >> 6] = v;
    __syncthreads();
    if (t == 0) out[b] = sigf(redL[0] + redL[1] + redL[2] + redL[3] + fc_b[0]);
  }
}

extern "C" void kernel_launch(void* const* d_in, const int* in_sizes, int n_in,
                              void* d_out, int out_size, void* d_ws, size_t ws_size,
                              hipStream_t stream) {
  const int*   x      = (const int*)d_in[0];
  const int*   mask   = (const int*)d_in[1];
  const float* embed  = (const float*)d_in[3];
  const float* W_ih   = (const float*)d_in[4];
  const float* W_hh   = (const float*)d_in[5];
  const float* b_ih   = (const float*)d_in[6];
  const float* b_hh   = (const float*)d_in[7];
  const float* Ws_w   = (const float*)d_in[8];
  const float* Ws_b   = (const float*)d_in[9];
  const float* Us_w   = (const float*)d_in[10];
  const float* Wx     = (const float*)d_in[12];
  const float* Wh     = (const float*)d_in[13];
  const float* Wm     = (const float*)d_in[14];
  const float* b_cell = (const float*)d_in[15];
  const float* fc_w   = (const float*)d_in[16];
  const float* fc_b   = (const float*)d_in[17];
  float* ws  = (float*)d_ws;
  float* out = (float*)d_out;

  k1_precompute<<<dim3(1152), dim3(256), 0, stream>>>(
      x, embed, W_ih, b_ih, b_hh, Ws_w, Ws_b, Wx, b_cell, ws);
  k2_shared_lstm<<<dim3(128), dim3(512), 0, stream>>>(W_hh, ws);
  k3_precompute2<<<dim3(640), dim3(256), 0, stream>>>(Ws_w, Wm, ws);
  k4_task_lstm<<<dim3(128), dim3(512), 0, stream>>>(
      mask, Ws_w, Us_w, Wh, fc_w, fc_b, ws, out);
}